// Round 2
// baseline (1954.210 us; speedup 1.0000x reference)
//
#include <hip/hip_runtime.h>
#include <hip/hip_bf16.h>
#include <cstdint>
#include <cstddef>

#define D 512
#define NHEAD 8
#define HD 64
#define LMAX 512
#define NGIN 3

// ---------------- dtype probe + normalization ----------------
// flags[0] = 1 if ptr/edge_index are int64 on device, 0 if int32
// flags[1] = mask element byte width (1, 4, or 8)
__global__ void probe_kernel(const int* __restrict__ ptr_raw,
                             const unsigned char* __restrict__ mask_raw,
                             int* __restrict__ flags){
    if (threadIdx.x == 0){
        // int32 ptr: ptr[1] = first graph size (>=256, nonzero).
        // int64 ptr: int32 slot 1 = high half of ptr[0]=0 -> zero.
        flags[0] = (ptr_raw[1] == 0) ? 1 : 0;
        int cntOdd = 0, cnt4 = 0;
        for (int i = 1; i < 2048; i += 2) cntOdd += (mask_raw[i] != 0);
        for (int i = 4; i < 2048; i += 8) cnt4   += (mask_raw[i] != 0);
        // bool(1B): odd bytes ~50% nonzero. int32: only offsets %4==0 nonzero.
        // int64: only offsets %8==0 nonzero.
        flags[1] = (cntOdd > 64) ? 1 : ((cnt4 > 16) ? 4 : 8);
    }
}

__global__ void conv_int_kernel(const int* __restrict__ raw, int* __restrict__ outp,
                                const int* __restrict__ flags, int n){
    int i = blockIdx.x*256 + threadIdx.x;
    if (i < n) outp[i] = flags[0] ? raw[2*i] : raw[i];   // little-endian low word
}

__global__ void conv_mask_kernel(const unsigned char* __restrict__ raw,
                                 unsigned char* __restrict__ outp,
                                 const int* __restrict__ flags, int n){
    int w = flags[1];
    int i = blockIdx.x*256 + threadIdx.x;
    if (i < n) outp[i] = raw[(size_t)i * w];   // value is 0/1 -> low byte suffices
}

// ---------------- CSR inversion (incoming-edge lists) ----------------
__global__ void count_kernel(const int* __restrict__ ei, int* __restrict__ deg, int E, int N){
    int e = blockIdx.x*256 + threadIdx.x;
    if (e < E){
        int d = ei[E + e];
        if ((unsigned)d < (unsigned)N) atomicAdd(&deg[d], 1);
    }
}

__global__ void scan_kernel(const int* __restrict__ deg, int* __restrict__ offs, int n){
    __shared__ int buf[1024];
    __shared__ int carry_s;
    int tid = threadIdx.x;
    if (tid == 0){ carry_s = 0; offs[0] = 0; }
    __syncthreads();
    int nChunks = (n + 1023) / 1024;
    for (int ch = 0; ch < nChunks; ch++){
        int i = ch*1024 + tid;
        int val = (i < n) ? deg[i] : 0;
        buf[tid] = val;
        __syncthreads();
        for (int off = 1; off < 1024; off <<= 1){
            int t = (tid >= off) ? buf[tid - off] : 0;
            __syncthreads();
            buf[tid] += t;
            __syncthreads();
        }
        if (i < n) offs[i+1] = carry_s + buf[tid];
        __syncthreads();
        if (tid == 0) carry_s += buf[1023];
        __syncthreads();
    }
}

__global__ void fill_kernel(const int* __restrict__ ei, const int* __restrict__ offs,
                            int* __restrict__ cursor, int* __restrict__ in_src, int E, int N){
    int e = blockIdx.x*256 + threadIdx.x;
    if (e < E){
        int d = ei[E + e];
        if ((unsigned)d < (unsigned)N){
            int slot = atomicAdd(&cursor[d], 1);
            in_src[offs[d] + slot] = ei[e];
        }
    }
}

// ---------------- gather: out[n] = h[n] + sum_{incoming} h[src] ----------------
__global__ __launch_bounds__(256) void gather_kernel(const float* __restrict__ h,
        const int* __restrict__ offs, const int* __restrict__ in_src,
        float* __restrict__ out){
    int node = blockIdx.x;
    int tid = threadIdx.x;
    const float* hr = h + (size_t)node*D;
    float a0 = hr[tid], a1 = hr[tid+256];
    int s = offs[node], e = offs[node+1];
    for (int i = s; i < e; i++){
        const float* hs = h + (size_t)in_src[i]*D;
        a0 += hs[tid]; a1 += hs[tid+256];
    }
    float* orow = out + (size_t)node*D;
    orow[tid] = a0; orow[tid+256] = a1;
}

// ---------------- generic f32 GEMM: C = act(A[M,K] @ W[K,Nout] + bias) ----------------
template<int ACT>
__global__ __launch_bounds__(256) void gemm_kernel(const float* __restrict__ A,
        const float* __restrict__ W, const float* __restrict__ bias,
        float* __restrict__ C, int K, int Nout){
    __shared__ float As[16][68];
    __shared__ float Ws[16][68];
    int tid = threadIdx.x;
    int rowBase = blockIdx.y * 64;
    int colBase = blockIdx.x * 64;
    int tx = tid & 15, ty = tid >> 4;
    int lrA = tid >> 2, lkA = (tid & 3) * 4;
    int lkW = tid >> 4, lcW = (tid & 15) * 4;
    float acc[4][4] = {};
    const float* Arow = A + (size_t)(rowBase + lrA)*K;
    for (int k0 = 0; k0 < K; k0 += 16){
        float4 a4 = *(const float4*)(Arow + k0 + lkA);
        As[lkA+0][lrA] = a4.x; As[lkA+1][lrA] = a4.y;
        As[lkA+2][lrA] = a4.z; As[lkA+3][lrA] = a4.w;
        float4 w4 = *(const float4*)(W + (size_t)(k0 + lkW)*Nout + colBase + lcW);
        *(float4*)&Ws[lkW][lcW] = w4;
        __syncthreads();
        #pragma unroll
        for (int k = 0; k < 16; k++){
            float4 av = *(const float4*)&As[k][ty*4];
            float4 wv = *(const float4*)&Ws[k][tx*4];
            float a_[4] = {av.x, av.y, av.z, av.w};
            float w_[4] = {wv.x, wv.y, wv.z, wv.w};
            #pragma unroll
            for (int i = 0; i < 4; i++)
                #pragma unroll
                for (int j = 0; j < 4; j++)
                    acc[i][j] += a_[i] * w_[j];
        }
        __syncthreads();
    }
    #pragma unroll
    for (int i = 0; i < 4; i++){
        int row = rowBase + ty*4 + i;
        float4 o;
        o.x = acc[i][0] + bias[colBase + tx*4 + 0];
        o.y = acc[i][1] + bias[colBase + tx*4 + 1];
        o.z = acc[i][2] + bias[colBase + tx*4 + 2];
        o.w = acc[i][3] + bias[colBase + tx*4 + 3];
        if (ACT){
            o.x = fmaxf(o.x, 0.f); o.y = fmaxf(o.y, 0.f);
            o.z = fmaxf(o.z, 0.f); o.w = fmaxf(o.w, 0.f);
        }
        *(float4*)(C + (size_t)row*Nout + colBase + tx*4) = o;
    }
}

// ---------------- BatchNorm ----------------
__global__ __launch_bounds__(256) void bn_stats_kernel(const float* __restrict__ A,
        float* __restrict__ sums, int n){
    int c = threadIdx.x;
    int r0 = blockIdx.x*128, r1 = min(n, r0+128);
    float s0=0.f, s1=0.f, q0=0.f, q1=0.f;
    for (int r = r0; r < r1; r++){
        float v0 = A[(size_t)r*D + c];
        float v1 = A[(size_t)r*D + 256 + c];
        s0 += v0; q0 += v0*v0; s1 += v1; q1 += v1*v1;
    }
    atomicAdd(&sums[c], s0);
    atomicAdd(&sums[c+256], s1);
    atomicAdd(&sums[512+c], q0);
    atomicAdd(&sums[512+c+256], q1);
}

__global__ void bn_final_kernel(const float* __restrict__ sums, const float* __restrict__ gamma,
        const float* __restrict__ beta, float* __restrict__ sc, int n){
    int c = threadIdx.x;        // 512 threads
    float mean = sums[c] / (float)n;
    float var = sums[512+c] / (float)n - mean*mean;
    float r = rsqrtf(var + 1e-5f);
    float scale = r * gamma[c];
    sc[c] = scale;
    sc[512+c] = beta[c] - mean*scale;
}

__global__ void bn_apply_kernel(const float* __restrict__ in, const float* __restrict__ sc,
        float* __restrict__ out, int total4){
    int i = blockIdx.x*256 + threadIdx.x;
    if (i >= total4) return;
    int c4 = (i*4) & (D-1);
    float4 vv = *(const float4*)(in + (size_t)i*4);
    float4 s  = *(const float4*)(sc + c4);
    float4 sh = *(const float4*)(sc + 512 + c4);
    float4 o;
    o.x = vv.x*s.x + sh.x; o.y = vv.y*s.y + sh.y;
    o.z = vv.z*s.z + sh.z; o.w = vv.w*s.w + sh.w;
    *(float4*)(out + (size_t)i*4) = o;
}

// ---------------- ragged masked flash attention ----------------
// grid: (LMAX/16, NHEAD, B). block: 256 threads = 4 waves, each wave 4 query rows.
__global__ __launch_bounds__(256) void attn_kernel(const float* __restrict__ qk,
        const float* __restrict__ v, const unsigned char* __restrict__ mask,
        const int* __restrict__ ptr, float* __restrict__ out, int N){
    __shared__ float Kt[64][65];   // [d][key]
    __shared__ float Vs[64][68];   // [key][d]
    __shared__ float Qs[16][68];   // [row][d]
    __shared__ float Ps[4][64];    // per-wave p vector
    int b = blockIdx.z, h = blockIdx.y;
    int base = ptr[b];
    int size = ptr[b+1] - base;
    if (base < 0) base = 0; if (base > N) base = N;
    if (size < 0) size = 0; if (size > N - base) size = N - base;
    int rowBase = blockIdx.x * 16;
    if (rowBase >= size) return;
    int tid = threadIdx.x;
    int w = tid >> 6, lane = tid & 63;
    {
        int rl = tid >> 4, c4 = (tid & 15) * 4;
        int r = rowBase + rl;
        float4 q4 = make_float4(0.f, 0.f, 0.f, 0.f);
        if (r < size)
            q4 = *(const float4*)(qk + (size_t)(base + r)*1024 + 512 + h*64 + c4);
        *(float4*)&Qs[rl][c4] = q4;
    }
    float m[4], l[4], acc[4];
    #pragma unroll
    for (int i = 0; i < 4; i++){ m[i] = -INFINITY; l[i] = 0.f; acc[i] = 0.f; }
    int nt = (size + 63) >> 6;
    for (int t = 0; t < nt; t++){
        int jBase = t * 64;
        __syncthreads();
        #pragma unroll
        for (int p = 0; p < 4; p++){
            int idx = tid + p*256;
            int rl = idx >> 4, c4 = (idx & 15) * 4;
            int j = jBase + rl;
            float4 kk = make_float4(0.f,0.f,0.f,0.f), vv = make_float4(0.f,0.f,0.f,0.f);
            if (j < size){
                size_t node = (size_t)(base + j);
                kk = *(const float4*)(qk + node*1024 + h*64 + c4);
                vv = *(const float4*)(v  + node*512  + h*64 + c4);
            }
            Kt[c4+0][rl] = kk.x; Kt[c4+1][rl] = kk.y;
            Kt[c4+2][rl] = kk.z; Kt[c4+3][rl] = kk.w;
            *(float4*)&Vs[rl][c4] = vv;
        }
        __syncthreads();
        for (int ri = 0; ri < 4; ri++){
            int r = rowBase + w*4 + ri;
            if (r >= size) continue;
            int j = jBase + lane;
            float s = -INFINITY;
            if (j < size && !mask[((size_t)b*LMAX + r)*LMAX + j]){
                float dot = 0.f;
                const float* qrow = Qs[w*4 + ri];
                #pragma unroll
                for (int d = 0; d < 64; d++) dot += qrow[d] * Kt[d][lane];
                s = dot * 0.125f;
            }
            float tm = s;
            #pragma unroll
            for (int off = 32; off > 0; off >>= 1) tm = fmaxf(tm, __shfl_xor(tm, off));
            if (tm == -INFINITY) continue;
            float mnew = fmaxf(m[ri], tm);
            float alpha = __expf(m[ri] - mnew);
            float p = (s == -INFINITY) ? 0.f : __expf(s - mnew);
            float psum = p;
            #pragma unroll
            for (int off = 32; off > 0; off >>= 1) psum += __shfl_xor(psum, off);
            m[ri] = mnew;
            l[ri] = l[ri]*alpha + psum;
            Ps[w][lane] = p;
            float a2 = 0.f;
            #pragma unroll
            for (int jj = 0; jj < 64; jj++) a2 += Ps[w][jj] * Vs[jj][lane];
            acc[ri] = acc[ri]*alpha + a2;
        }
    }
    #pragma unroll
    for (int ri = 0; ri < 4; ri++){
        int r = rowBase + w*4 + ri;
        if (r < size) out[(size_t)(base + r)*512 + h*64 + lane] = acc[ri] / l[ri];
    }
}

extern "C" void kernel_launch(void* const* d_in, const int* in_sizes, int n_in,
                              void* d_out, int out_size, void* d_ws, size_t ws_size,
                              hipStream_t stream){
    const float* x        = (const float*)d_in[0];
    const int*   ei_raw   = (const int*)d_in[1];
    const unsigned char* mask_raw = (const unsigned char*)d_in[2];
    const int*   ptr_raw  = (const int*)d_in[3];
    const float* gin_w1   = (const float*)d_in[4];
    const float* gin_b1   = (const float*)d_in[5];
    const float* gin_w2   = (const float*)d_in[6];
    const float* gin_b2   = (const float*)d_in[7];
    const float* bn_gamma = (const float*)d_in[8];
    const float* bn_beta  = (const float*)d_in[9];
    const float* se_w     = (const float*)d_in[10];
    const float* se_b     = (const float*)d_in[11];
    const float* qk_w     = (const float*)d_in[12];
    const float* qk_b     = (const float*)d_in[13];
    const float* v_w      = (const float*)d_in[14];
    const float* v_b      = (const float*)d_in[15];
    const float* out_w    = (const float*)d_in[16];
    const float* out_b    = (const float*)d_in[17];

    const int N = in_sizes[0] / D;        // 12160
    const int E = in_sizes[1] / 2;        // 97280
    const int B = in_sizes[3] - 1;        // 32
    const int Mn = in_sizes[2];           // B*L*L mask elements

    char* ws = (char*)d_ws;
    size_t NB = (size_t)N * D * sizeof(float);
    float* vbuf  = (float*)(ws);
    float* bufA  = (float*)(ws + NB);
    float* bufB  = (float*)(ws + 2*NB);
    float* bufC  = (float*)(ws + 3*NB);
    float* qkbuf = bufA;                   // spans [NB, 3NB) when A/B are dead
    char* p = ws + 4*NB;
    float* sums   = (float*)p; p += 1024*sizeof(float);
    float* sc     = (float*)p; p += 1024*sizeof(float);
    int*   flags  = (int*)p;   p += 16*sizeof(int);
    int*   deg    = (int*)p;   p += (size_t)N*sizeof(int);
    int*   offs   = (int*)p;   p += (size_t)(N+1)*sizeof(int);
    int*   cursor = (int*)p;   p += (size_t)N*sizeof(int);
    int*   in_src = (int*)p;   p += (size_t)E*sizeof(int);
    int*   ptr32  = (int*)p;   p += 64*sizeof(int);
    int*   ei32   = (int*)p;   p += (size_t)2*E*sizeof(int);
    unsigned char* mask8 = (unsigned char*)p; p += (size_t)Mn;

    // --- dtype probe + normalization ---
    probe_kernel<<<1, 64, 0, stream>>>(ptr_raw, mask_raw, flags);
    conv_int_kernel<<<1, 64, 0, stream>>>(ptr_raw, ptr32, flags, B + 1);
    conv_int_kernel<<<(2*E + 255)/256, 256, 0, stream>>>(ei_raw, ei32, flags, 2*E);
    conv_mask_kernel<<<(Mn + 255)/256, 256, 0, stream>>>(mask_raw, mask8, flags, Mn);

    // --- invert edges into incoming CSR ---
    hipMemsetAsync(deg, 0, (size_t)N*sizeof(int), stream);
    hipMemsetAsync(cursor, 0, (size_t)N*sizeof(int), stream);
    count_kernel<<<(E+255)/256, 256, 0, stream>>>(ei32, deg, E, N);
    scan_kernel<<<1, 1024, 0, stream>>>(deg, offs, N);
    fill_kernel<<<(E+255)/256, 256, 0, stream>>>(ei32, offs, cursor, in_src, E, N);

    dim3 g512(512/64, N/64), g1024(1024/64, N/64);

    // v = x @ v_w + v_b
    gemm_kernel<0><<<g512, 256, 0, stream>>>(x, v_w, v_b, vbuf, D, D);

    // GIN layers
    const float* h = x;
    for (int i = 0; i < NGIN; i++){
        gather_kernel<<<N, 256, 0, stream>>>(h, offs, in_src, bufB);
        gemm_kernel<1><<<g512, 256, 0, stream>>>(bufB, gin_w1 + (size_t)i*D*D, gin_b1 + (size_t)i*D, bufC, D, D);
        gemm_kernel<1><<<g512, 256, 0, stream>>>(bufC, gin_w2 + (size_t)i*D*D, gin_b2 + (size_t)i*D, bufA, D, D);
        h = bufA;
    }

    // BatchNorm (batch stats, biased var)
    hipMemsetAsync(sums, 0, 1024*sizeof(float), stream);
    bn_stats_kernel<<<(N+127)/128, 256, 0, stream>>>(bufA, sums, N);
    bn_final_kernel<<<1, 512, 0, stream>>>(sums, bn_gamma, bn_beta, sc, N);
    bn_apply_kernel<<<(N*D/4 + 255)/256, 256, 0, stream>>>(bufA, sc, bufB, N*D/4);

    // x_struct = bn(h) @ se_w + se_b
    gemm_kernel<0><<<g512, 256, 0, stream>>>(bufB, se_w, se_b, bufC, D, D);

    // qk = x_struct @ qk_w + qk_b   (k = [:, :512], q = [:, 512:])
    gemm_kernel<0><<<g1024, 256, 0, stream>>>(bufC, qk_w, qk_b, qkbuf, D, 1024);

    // attention -> bufC
    attn_kernel<<<dim3(LMAX/16, NHEAD, B), 256, 0, stream>>>(qkbuf, vbuf, mask8, ptr32, bufC, N);

    // out = attn_out @ out_w + out_b
    gemm_kernel<0><<<g512, 256, 0, stream>>>(bufC, out_w, out_b, (float*)d_out, D, D);
}